// Round 2
// baseline (131.251 us; speedup 1.0000x reference)
//
#include <hip/hip_runtime.h>

// IGANN: per-feature 2-layer MLPs (1->16->16->1), summed over 256 features + linear term.
// Strategy: f16-input MFMA (fp32 accum) for the per-feature 16x16 fc2 GEMM.
//   wave = 64 batch rows (4 MFMA row-tiles) x 32 features; 8 feature-groups -> atomicAdd.
//   grid 1024 blocks (4/CU), block 256 (4 waves).

typedef float    f32x4 __attribute__((ext_vector_type(4)));
typedef _Float16 f16x4 __attribute__((ext_vector_type(4)));
typedef _Float16 f16x8 __attribute__((ext_vector_type(8)));

#if __has_builtin(__builtin_amdgcn_mfma_f32_16x16x16f16)
#define USE_K16 1
#define MFMA16F16 __builtin_amdgcn_mfma_f32_16x16x16f16
#elif __has_builtin(__builtin_amdgcn_mfma_f32_16x16x16_f16)
#define USE_K16 1
#define MFMA16F16 __builtin_amdgcn_mfma_f32_16x16x16_f16
#else
#define USE_K16 0   // fallback: 16x16x32 with K duplicated (result = 2x true, scale 0.5)
#endif

__device__ __forceinline__ f16x4 cvt4(f32x4 v) {
    f16x4 r;
    r[0] = (_Float16)v[0];
    r[1] = (_Float16)v[1];
    r[2] = (_Float16)v[2];
    r[3] = (_Float16)v[3];
    return r;
}

#define FCHUNK 32   // features per block (8 groups of 32 = 256)

__global__ __launch_bounds__(256) void igann_kernel(
    const float* __restrict__ x,  const float* __restrict__ la,
    const float* __restrict__ bb, const float* __restrict__ W1,
    const float* __restrict__ b1, const float* __restrict__ W2,
    const float* __restrict__ b2, const float* __restrict__ W3,
    const float* __restrict__ b3, float* __restrict__ out)
{
    const int tid = threadIdx.x;
    const int l   = tid & 63;     // lane
    const int w   = tid >> 6;     // wave in block (0..3)
    const int r   = l & 15;       // MFMA row (A) / col n (B,D)
    const int g   = l >> 4;       // k-group
    const int g4  = g * 4;
    const int r16 = r * 16;

    const int rb = blockIdx.x >> 3;   // row block (0..127), 256 rows each
    const int fg = blockIdx.x & 7;    // feature group (0..7) -> XCD via %8 dispatch
    const int f0 = fg * FCHUNK;
    const int b0 = rb * 256 + w * 64; // this wave's first row (owns 64 rows = 4 tiles)

    // per-lane x row pointer (tile t adds 16*256 floats)
    const float* xr0 = x + (size_t)(b0 + r) * 256 + f0;

    f32x4 acc[4];     // [tile][reg j]: D-layout rows g*4+j, col r
    float lin[4];     // linear term partial for row r of each tile
    #pragma unroll
    for (int t = 0; t < 4; ++t) { acc[t] = (f32x4){0.f,0.f,0.f,0.f}; lin[t] = 0.f; }
    float b3s = 0.f;

    for (int fi = 0; fi < FCHUNK; fi += 4) {
        f32x4 xv[4];
        #pragma unroll
        for (int t = 0; t < 4; ++t)
            xv[t] = *(const f32x4*)(xr0 + t * 16 * 256 + fi);

        #pragma unroll
        for (int u = 0; u < 4; ++u) {
            const int f = f0 + fi + u;
#if USE_K16
            // A needs h1[m=r][k=g*4+j]; B needs W2[f][n=r][k=g*4+j]
            f32x4 w1  = *(const f32x4*)(W1 + f * 16 + g4);
            f32x4 bb1 = *(const f32x4*)(b1 + f * 16 + g4);
            f32x4 w2  = *(const f32x4*)(W2 + (size_t)f * 256 + r16 + g4);
            f16x4 bfrag = cvt4(w2);
#else
            const int kb = (g & 1) * 8;   // duplicate K halves; D = 2x true
            f32x4 w1  = *(const f32x4*)(W1 + f * 16 + kb);
            f32x4 w1h = *(const f32x4*)(W1 + f * 16 + kb + 4);
            f32x4 bb1 = *(const f32x4*)(b1 + f * 16 + kb);
            f32x4 bb1h= *(const f32x4*)(b1 + f * 16 + kb + 4);
            f32x4 w2  = *(const f32x4*)(W2 + (size_t)f * 256 + r16 + kb);
            f32x4 w2h = *(const f32x4*)(W2 + (size_t)f * 256 + r16 + kb + 4);
            f16x4 blo = cvt4(w2), bhi = cvt4(w2h);
            f16x8 bfrag;
            #pragma unroll
            for (int j = 0; j < 4; ++j) { bfrag[j] = blo[j]; bfrag[4 + j] = bhi[j]; }
#endif
            const float b2k = b2[f * 16 + r];
            const float w3k = W3[f * 16 + r];
            b3s += b3[f];
            const float av = la[f];

            #pragma unroll
            for (int t = 0; t < 4; ++t) {
                const float xs = xv[t][u];
                lin[t] = fmaf(xs, av, lin[t]);
#if USE_K16
                f32x4 h1;
                #pragma unroll
                for (int j = 0; j < 4; ++j)
                    h1[j] = fmaxf(fmaf(xs, w1[j], bb1[j]), 0.f);
                f16x4 afrag = cvt4(h1);
                f32x4 d = MFMA16F16(afrag, bfrag, (f32x4){0.f,0.f,0.f,0.f}, 0, 0, 0);
                #pragma unroll
                for (int j = 0; j < 4; ++j)
                    acc[t][j] += fmaxf(d[j] + b2k, 0.f) * w3k;
#else
                f32x4 h1a, h1b;
                #pragma unroll
                for (int j = 0; j < 4; ++j) {
                    h1a[j] = fmaxf(fmaf(xs, w1[j],  bb1[j]),  0.f);
                    h1b[j] = fmaxf(fmaf(xs, w1h[j], bb1h[j]), 0.f);
                }
                f16x4 alo = cvt4(h1a), ahi = cvt4(h1b);
                f16x8 afrag;
                #pragma unroll
                for (int j = 0; j < 4; ++j) { afrag[j] = alo[j]; afrag[4 + j] = ahi[j]; }
                f32x4 d = __builtin_amdgcn_mfma_f32_16x16x32_f16(
                    afrag, bfrag, (f32x4){0.f,0.f,0.f,0.f}, 0, 0, 0);
                #pragma unroll
                for (int j = 0; j < 4; ++j)
                    acc[t][j] += fmaxf(fmaf(0.5f, d[j], b2k), 0.f) * w3k;
#endif
            }
        }
    }

    // reduce over the 16 kout columns (lanes differing in bits 0..3)
    #pragma unroll
    for (int t = 0; t < 4; ++t)
        #pragma unroll
        for (int j = 0; j < 4; ++j) {
            float v = acc[t][j];
            v += __shfl_xor(v, 1, 64);
            v += __shfl_xor(v, 2, 64);
            v += __shfl_xor(v, 4, 64);
            v += __shfl_xor(v, 8, 64);
            acc[t][j] = v;
        }

    __shared__ float red[4][4][16];   // [wave][tile][row]
    if (r == 0) {
        #pragma unroll
        for (int t = 0; t < 4; ++t)
            #pragma unroll
            for (int j = 0; j < 4; ++j)
                red[w][t][g4 + j] = acc[t][j];
    }
    __syncthreads();

    const float gconst = b3s + (fg == 0 ? bb[0] : 0.f);
    if (l < 16) {
        #pragma unroll
        for (int t = 0; t < 4; ++t) {
            const float v = red[w][t][l] + lin[t] + gconst;
            atomicAdd(out + b0 + t * 16 + l, v);
        }
    }
}

extern "C" void kernel_launch(void* const* d_in, const int* in_sizes, int n_in,
                              void* d_out, int out_size, void* d_ws, size_t ws_size,
                              hipStream_t stream) {
    const float* x  = (const float*)d_in[0];
    const float* la = (const float*)d_in[1];
    const float* bb = (const float*)d_in[2];
    const float* W1 = (const float*)d_in[3];
    const float* b1 = (const float*)d_in[4];
    const float* W2 = (const float*)d_in[5];
    const float* b2 = (const float*)d_in[6];
    const float* W3 = (const float*)d_in[7];
    const float* b3 = (const float*)d_in[8];
    float* out = (float*)d_out;

    // 8 feature-groups accumulate via atomicAdd -> zero first (d_out is poisoned 0xAA)
    (void)hipMemsetAsync(out, 0, (size_t)out_size * sizeof(float), stream);

    dim3 grid(1024), block(256);
    hipLaunchKernelGGL(igann_kernel, grid, block, 0, stream,
                       x, la, bb, W1, b1, W2, b2, W3, b3, out);
}